// Round 8
// baseline (70.124 us; speedup 1.0000x reference)
//
#include <hip/hip_runtime.h>
#include <math.h>

#define NE 32
#define HID 2880
#define TT 256           // tokens per block (4 halves of 64; all share W reads)
#define THREADS 512      // 8 waves = 2 (expert-half) x 4 (k-slot)
#define CK 16            // k-chunk staged in LDS

// global_load_lds: wave-uniform LDS dest + lane*16; per-lane global src.
#define GLL(gsrc, ldst)                                                        \
  __builtin_amdgcn_global_load_lds(                                            \
      (const __attribute__((address_space(1))) unsigned int*)(gsrc),           \
      (__attribute__((address_space(3))) unsigned int*)(ldst), 16, 0, 0)

// h LDS swizzle: physical slot (prow, ps) <- logical (row, s):
//   prow = row ^ ((row>>2)&1), ps = s ^ (row&3)      (bijective; inverse below)
// Compute-read byte mod 128 sweeps all 8 16B-positions over 8 rows -> b128
// reads by 64 lanes are conflict-free (8 lanes per position, the minimum).

__global__ void __launch_bounds__(THREADS, 4) router_part(
    const float* __restrict__ hs,   // [T][HID]
    const float* __restrict__ w,    // [NE][HID]
    float* __restrict__ wsp,        // [KQ][T][NE] partial logits
    int T, int klen, int nchunk, int ntg)
{
  __shared__ float smem[10240];     // 40960 B:
  // loop phase:  hbuf0 = smem[0..4095], hbuf1 = smem[4096..8191],
  //              wbuf0 = smem[8192..8703], wbuf1 = smem[8704..9215]
  // epilogue:    part[eg][256][20] overlay = smem[0..10239]

  const int tid  = threadIdx.x;
  const int wv   = __builtin_amdgcn_readfirstlane(tid >> 6);
  const int lane = tid & 63;
  const int eg   = wv >> 2;         // experts [eg*16, +16)
  const int kg   = wv & 3;          // k-slot [kg*4, +4) within chunk
  const int tg   = blockIdx.x % ntg;
  const int kq   = blockIdx.x / ntg;
  const int t0   = tg * TT;
  const int k0   = kq * klen;

  // ---- h staging offsets (inverse swizzle): linear slot f -> (row, s) ----
  int goffH[2];
#pragma unroll
  for (int i = 0; i < 2; ++i) {
    int f   = tid + THREADS * i;    // 0..1023 16B-slots per chunk
    int pr  = f >> 2;
    int ps  = f & 3;
    int row = pr ^ ((pr >> 2) & 1);
    int s   = ps ^ (row & 3);
    goffH[i] = row * HID + s * 4;   // float offset within chunk
  }
  // W staging (tid<128): slot f <- w[f/4][(f%4)*4 ..] linear (broadcast reads)
  const int goffW = (tid >> 2) * HID + (tid & 3) * 4;

  // ---- compute-read offset: rows h*64+lane, col-group kg, swizzled ----
  const int plane = lane ^ ((lane >> 2) & 1);
  const int hoff  = plane * 16 + (kg ^ (lane & 3)) * 4;  // + h*1024 floats

  float acc[4][16];
#pragma unroll
  for (int h = 0; h < 4; ++h)
#pragma unroll
    for (int e = 0; e < 16; ++e) acc[h][e] = 0.f;

  // ---- prologue: stage chunk 0 ----
  {
    const float* hsrc = hs + (size_t)t0 * HID + k0;
    GLL(hsrc + goffH[0], (char*)smem + tid * 16);
    GLL(hsrc + goffH[1], (char*)smem + (tid + THREADS) * 16);
    if (tid < 128) GLL(w + k0 + goffW, (char*)(smem + 8192) + tid * 16);
  }
  __syncthreads();   // compiler drains vmcnt before s_barrier

#pragma clang loop unroll(disable)
  for (int c = 0; c < nchunk; ++c) {
    const float* hb = smem + (c & 1) * 4096;
    const float* wb = smem + 8192 + (c & 1) * 512;

    // issue next chunk's staging (async; lands before next barrier's drain)
    if (c + 1 < nchunk) {
      char* hb_n = (char*)smem + ((c & 1) ^ 1) * 16384;
      char* wb_n = (char*)(smem + 8192) + ((c & 1) ^ 1) * 2048;
      const float* hsrc = hs + (size_t)t0 * HID + k0 + (c + 1) * CK;
      GLL(hsrc + goffH[0], hb_n + tid * 16);
      GLL(hsrc + goffH[1], hb_n + (tid + THREADS) * 16);
      if (tid < 128) GLL(w + k0 + (c + 1) * CK + goffW, wb_n + tid * 16);
    }

    // ---- h fragments: one b128 per token-half (conflict-free swizzle) ----
    float4 ha = *(const float4*)(hb + hoff);
    float4 hbv = *(const float4*)(hb + 1024 + hoff);
    float4 hc = *(const float4*)(hb + 2048 + hoff);
    float4 hd = *(const float4*)(hb + 3072 + hoff);

    // ---- 16 experts x 16 FMAs each; W via wave-uniform broadcast b128,
    //      grouped by 4 to bound the live W-register window ----
    const float* wub = wb + eg * 256 + kg * 4;
#pragma unroll
    for (int g4 = 0; g4 < 4; ++g4) {
      float4 w0 = *(const float4*)(wub + (g4 * 4 + 0) * 16);
      float4 w1 = *(const float4*)(wub + (g4 * 4 + 1) * 16);
      float4 w2 = *(const float4*)(wub + (g4 * 4 + 2) * 16);
      float4 w3 = *(const float4*)(wub + (g4 * 4 + 3) * 16);
#define EFMA(we, ei)                                                           \
      {                                                                        \
        const int e = g4 * 4 + ei;                                             \
        acc[0][e] = fmaf(ha.w, we.w, fmaf(ha.z, we.z,                          \
                    fmaf(ha.y, we.y, fmaf(ha.x, we.x, acc[0][e]))));           \
        acc[1][e] = fmaf(hbv.w, we.w, fmaf(hbv.z, we.z,                        \
                    fmaf(hbv.y, we.y, fmaf(hbv.x, we.x, acc[1][e]))));         \
        acc[2][e] = fmaf(hc.w, we.w, fmaf(hc.z, we.z,                          \
                    fmaf(hc.y, we.y, fmaf(hc.x, we.x, acc[2][e]))));           \
        acc[3][e] = fmaf(hd.w, we.w, fmaf(hd.z, we.z,                          \
                    fmaf(hd.y, we.y, fmaf(hd.x, we.x, acc[3][e]))));           \
      }
      EFMA(w0, 0) EFMA(w1, 1) EFMA(w2, 2) EFMA(w3, 3)
#undef EFMA
    }

    __syncthreads();  // readers done with c; vmcnt drained (c+1 staged)
  }

  // ---- reduce 4 kg-waves into part[eg][256][20] overlay ----
#pragma unroll
  for (int ph = 0; ph < 4; ++ph) {
    if (kg == ph) {
#pragma unroll
      for (int h = 0; h < 4; ++h) {
        int row = h * 64 + lane;
        float* pp = smem + (eg * 256 + row) * 20;
        if (ph == 0) {
#pragma unroll
          for (int q = 0; q < 4; ++q) {
            float4 v;
            v.x = acc[h][q*4+0]; v.y = acc[h][q*4+1];
            v.z = acc[h][q*4+2]; v.w = acc[h][q*4+3];
            *(float4*)(pp + q * 4) = v;
          }
        } else {
#pragma unroll
          for (int q = 0; q < 4; ++q) {
            float4 v = *(float4*)(pp + q * 4);
            v.x += acc[h][q*4+0]; v.y += acc[h][q*4+1];
            v.z += acc[h][q*4+2]; v.w += acc[h][q*4+3];
            *(float4*)(pp + q * 4) = v;
          }
        }
      }
    }
    __syncthreads();
  }

  // ---- write partial logits [kq][t0+tok][32], coalesced float4 ----
  float* dst = wsp + ((size_t)kq * T + t0) * NE;
#pragma unroll
  for (int i = 0; i < 4; ++i) {
    int idx = tid + THREADS * i;    // 0..2047 float4 slots
    int tok = idx >> 3;
    int g   = idx & 7;
    float4 v = *(float4*)(smem + ((g >> 2) * 256 + tok) * 20 + (g & 3) * 4);
    *(float4*)(dst + tok * NE + g * 4) = v;
  }
}

__global__ void __launch_bounds__(64) router_topk(
    const float* __restrict__ wsp,  // [KQ][T][NE]
    const float* __restrict__ bias, // [NE]
    float* __restrict__ out,        // [T][NE] scores, then [T][4] idx-as-float
    int T, int KQ)
{
  const int tok = blockIdx.x * 64 + threadIdx.x;

  float lg[NE];
#pragma unroll
  for (int e = 0; e < NE; e += 4) {
    float4 bb = *(const float4*)(bias + e);
    lg[e] = bb.x; lg[e+1] = bb.y; lg[e+2] = bb.z; lg[e+3] = bb.w;
  }
  for (int q = 0; q < KQ; ++q) {
    const float* p = wsp + ((size_t)q * T + tok) * NE;
#pragma unroll
    for (int e = 0; e < NE; e += 4) {
      float4 v = *(const float4*)(p + e);
      lg[e] += v.x; lg[e+1] += v.y; lg[e+2] += v.z; lg[e+3] += v.w;
    }
  }

  float tv[4]; int ti[4];
#pragma unroll
  for (int kk = 0; kk < 4; ++kk) {
    float m = -INFINITY; int mi = 0;
#pragma unroll
    for (int e = 0; e < NE; ++e) {
      bool gt = lg[e] > m;        // strict >: lowest index wins ties (jax)
      m  = gt ? lg[e] : m;
      mi = gt ? e : mi;
    }
    tv[kk] = m; ti[kk] = mi;
#pragma unroll
    for (int e = 0; e < NE; ++e)
      lg[e] = (e == mi) ? -INFINITY : lg[e];
  }

  float e1 = __expf(tv[1] - tv[0]);
  float e2 = __expf(tv[2] - tv[0]);
  float e3 = __expf(tv[3] - tv[0]);
  float inv = 1.0f / (1.0f + e1 + e2 + e3);
  float pr[4] = {inv, e1 * inv, e2 * inv, e3 * inv};

  float* orow = out + (size_t)tok * NE;
#pragma unroll
  for (int g = 0; g < 8; ++g) {
    float4 v;
    float* vp = (float*)&v;
#pragma unroll
    for (int cb = 0; cb < 4; ++cb) {
      int e = g * 4 + cb;
      float x = 0.f;
      x = (e == ti[0]) ? pr[0] : x;
      x = (e == ti[1]) ? pr[1] : x;
      x = (e == ti[2]) ? pr[2] : x;
      x = (e == ti[3]) ? pr[3] : x;
      vp[cb] = x;
    }
    *(float4*)(orow + g * 4) = v;
  }
  float* oidx = out + (size_t)T * NE + (size_t)tok * 4;
  float4 iv;
  iv.x = (float)ti[0]; iv.y = (float)ti[1]; iv.z = (float)ti[2]; iv.w = (float)ti[3];
  *(float4*)oidx = iv;
}

extern "C" void kernel_launch(void* const* d_in, const int* in_sizes, int n_in,
                              void* d_out, int out_size, void* d_ws, size_t ws_size,
                              hipStream_t stream) {
  const float* hs   = (const float*)d_in[0];
  const float* w    = (const float*)d_in[1];
  const float* bias = (const float*)d_in[2];
  float* out        = (float*)d_out;
  float* wsp        = (float*)d_ws;

  const int T = in_sizes[0] / HID;      // 16384
  const int ntg = T / TT;               // 64

  // K-split chosen by workspace capacity (partials are [KQ][T][NE] fp32).
  const size_t per_kq = (size_t)T * NE * 4;
  int KQ = (ws_size >= 12 * per_kq) ? 12 : (ws_size >= 6 * per_kq) ? 6 : 4;
  const int klen   = HID / KQ;          // 240 / 480 / 720
  const int nchunk = klen / CK;         // 15 / 30 / 45

  hipLaunchKernelGGL(router_part, dim3(ntg * KQ), dim3(THREADS), 0, stream,
                     hs, w, wsp, T, klen, nchunk, ntg);
  hipLaunchKernelGGL(router_topk, dim3(T / 64), dim3(64), 0, stream,
                     wsp, bias, out, T, KQ);
}

// Round 9
// 52.563 us; speedup vs baseline: 1.3341x; 1.3341x over previous
//
#include <hip/hip_runtime.h>
#include <math.h>

#define NE 32
#define HID 2880
#define NSTEP 90          // 2880/32 k-steps total
#define TT 64             // tokens per block
#define THREADS 256       // 4 waves; wave wv owns tokens [t0+16*wv, +16)
#define WSB_BYTES (3 * NSTEP * 2 * 64 * 16)   // 552960 B of packed W fragments

typedef short bf16x8 __attribute__((ext_vector_type(8)));
typedef float f32x4 __attribute__((ext_vector_type(4)));

union FragU { uint4 q; bf16x8 v; };

// global_load_lds: wave-uniform LDS dest + lane*16; per-lane global src.
#define GLL(gsrc, ldst)                                                        \
  __builtin_amdgcn_global_load_lds(                                            \
      (const __attribute__((address_space(1))) unsigned int*)(gsrc),           \
      (__attribute__((address_space(3))) unsigned int*)(ldst), 16, 0, 0)

// ---------- kernel 0: split W into 3 bf16 limbs, packed as B-fragments ----
// wsB fragment (p, s, t): lane l holds 8 bf16 = W_p[t*16 + (l&15)][s*32 + (l>>4)*8 + j]
// stored as 4 dwords at int4-slot ((p*NSTEP + s)*2 + t)*64 + l.
__global__ void __launch_bounds__(256) wsplit_kernel(
    const float* __restrict__ w, unsigned int* __restrict__ wsB)
{
  const int gid = blockIdx.x * 256 + threadIdx.x;   // 0..11519
  const int s  = gid >> 7;
  const int tl = (gid >> 6) & 1;
  const int l  = gid & 63;

  const float* src = w + (size_t)(tl * 16 + (l & 15)) * HID + s * 32 + ((l >> 4) * 8);
  float4 xa = *(const float4*)src;
  float4 xb = *(const float4*)(src + 4);
  float x[8] = {xa.x, xa.y, xa.z, xa.w, xb.x, xb.y, xb.z, xb.w};

  unsigned int u0[8], u1[8], u2[8];
#pragma unroll
  for (int j = 0; j < 8; ++j) {
    unsigned int ux = __float_as_uint(x[j]);
    u0[j] = ux & 0xFFFF0000u;                       // limb0 (truncated bf16)
    float r1 = x[j] - __uint_as_float(u0[j]);       // exact
    u1[j] = __float_as_uint(r1) & 0xFFFF0000u;      // limb1
    float r2 = r1 - __uint_as_float(u1[j]);         // exact
    u2[j] = __float_as_uint(r2);                    // limb2 (trunc on pack)
  }

  uint4* dst = (uint4*)wsB;
  uint4 d;
  d.x = __builtin_amdgcn_perm(u0[1], u0[0], 0x07060302u);
  d.y = __builtin_amdgcn_perm(u0[3], u0[2], 0x07060302u);
  d.z = __builtin_amdgcn_perm(u0[5], u0[4], 0x07060302u);
  d.w = __builtin_amdgcn_perm(u0[7], u0[6], 0x07060302u);
  dst[((0 * NSTEP + s) * 2 + tl) * 64 + l] = d;
  d.x = __builtin_amdgcn_perm(u1[1], u1[0], 0x07060302u);
  d.y = __builtin_amdgcn_perm(u1[3], u1[2], 0x07060302u);
  d.z = __builtin_amdgcn_perm(u1[5], u1[4], 0x07060302u);
  d.w = __builtin_amdgcn_perm(u1[7], u1[6], 0x07060302u);
  dst[((1 * NSTEP + s) * 2 + tl) * 64 + l] = d;
  d.x = __builtin_amdgcn_perm(u2[1], u2[0], 0x07060302u);
  d.y = __builtin_amdgcn_perm(u2[3], u2[2], 0x07060302u);
  d.z = __builtin_amdgcn_perm(u2[5], u2[4], 0x07060302u);
  d.w = __builtin_amdgcn_perm(u2[7], u2[6], 0x07060302u);
  dst[((2 * NSTEP + s) * 2 + tl) * 64 + l] = d;
}

// ---------- kernel 1: MFMA GEMM partials -----------------------------------
__global__ void __launch_bounds__(THREADS, 4) router_mfma(
    const float* __restrict__ hs,         // [T][HID]
    const unsigned int* __restrict__ wsB, // packed W fragments
    float* __restrict__ wsp,              // [KQ][T][NE] fp32 partials
    int T, int KQ, int ntg)
{
  __shared__ float smem[2][TT * 64];      // [2][64 rows][64 k] fp32, 32 KB

  const int tid = threadIdx.x;
  const int wv  = __builtin_amdgcn_readfirstlane(tid >> 6);
  const int l   = tid & 63;
  const int q   = l >> 4;
  const int r15 = l & 15;
  const int tg  = blockIdx.x % ntg;
  const int kq  = blockIdx.x / ntg;
  const int t0  = tg * TT;

  int nsteps, s0;
  if (KQ == 4) { nsteps = (kq == 0) ? 24 : 22; s0 = (kq == 0) ? 0 : (2 + 22 * kq); }
  else         { nsteps = (kq == 0) ? 46 : 44; s0 = (kq == 0) ? 0 : 46; }
  const int nchunk = nsteps >> 1;         // 2 k-steps (64 k) per chunk

  // staging: 1024 granules/chunk; phys slot f holds logical granule
  // G = (f&15) ^ (row&15) of row = f>>4 (XOR swizzle via pre-swizzled source)
  int goff[4];
#pragma unroll
  for (int i = 0; i < 4; ++i) {
    int f = tid + 256 * i;
    int row = f >> 4;
    int G = (f & 15) ^ (row & 15);
    goff[i] = row * HID + G * 4;          // float offset within chunk
  }

  const int hrowb = (wv * 16 + r15) * 256;  // row byte base within buffer

  f32x4 acc0 = {0.f, 0.f, 0.f, 0.f};
  f32x4 acc1 = {0.f, 0.f, 0.f, 0.f};

  const float* hbase = hs + (size_t)t0 * HID + s0 * 32;

  // prologue: stage chunk 0
#pragma unroll
  for (int i = 0; i < 4; ++i)
    GLL(hbase + goff[i], (char*)smem + (tid + 256 * i) * 16);
  __syncthreads();

#pragma clang loop unroll(disable)
  for (int c = 0; c < nchunk; ++c) {
    if (c + 1 < nchunk) {
      const float* hn = hbase + (c + 1) * 64;
      char* bn = (char*)smem + ((c + 1) & 1) * 16384;
#pragma unroll
      for (int i = 0; i < 4; ++i)
        GLL(hn + goff[i], bn + (tid + 256 * i) * 16);
    }
    const char* cb = (const char*)smem + (c & 1) * 16384;

#pragma unroll
    for (int sl = 0; sl < 2; ++sl) {
      const int sg = s0 + c * 2 + sl;

      // W fragments: 6 x 16B, L1/L2-hot, per-lane coalesced
      const uint4* wb = (const uint4*)wsB;
      FragU W00, W01, W10, W11, W20, W21;
      W00.q = wb[((0 * NSTEP + sg) * 2 + 0) * 64 + l];
      W01.q = wb[((0 * NSTEP + sg) * 2 + 1) * 64 + l];
      W10.q = wb[((1 * NSTEP + sg) * 2 + 0) * 64 + l];
      W11.q = wb[((1 * NSTEP + sg) * 2 + 1) * 64 + l];
      W20.q = wb[((2 * NSTEP + sg) * 2 + 0) * 64 + l];
      W21.q = wb[((2 * NSTEP + sg) * 2 + 1) * 64 + l];

      // h: 8 fp32 via 2 swizzled ds_read_b128
      float4 h0 = *(const float4*)(cb + hrowb + (((sl * 8 + 2 * q + 0) ^ r15) << 4));
      float4 h1 = *(const float4*)(cb + hrowb + (((sl * 8 + 2 * q + 1) ^ r15) << 4));
      float x[8] = {h0.x, h0.y, h0.z, h0.w, h1.x, h1.y, h1.z, h1.w};

      // 3-way truncation split (exact residuals)
      unsigned int u0[8], u1[8], u2[8];
#pragma unroll
      for (int j = 0; j < 8; ++j) {
        unsigned int ux = __float_as_uint(x[j]);
        u0[j] = ux & 0xFFFF0000u;
        float r1 = x[j] - __uint_as_float(u0[j]);
        u1[j] = __float_as_uint(r1) & 0xFFFF0000u;
        float r2 = r1 - __uint_as_float(u1[j]);
        u2[j] = __float_as_uint(r2);
      }
      FragU A0, A1, A2;
      A0.q.x = __builtin_amdgcn_perm(u0[1], u0[0], 0x07060302u);
      A0.q.y = __builtin_amdgcn_perm(u0[3], u0[2], 0x07060302u);
      A0.q.z = __builtin_amdgcn_perm(u0[5], u0[4], 0x07060302u);
      A0.q.w = __builtin_amdgcn_perm(u0[7], u0[6], 0x07060302u);
      A1.q.x = __builtin_amdgcn_perm(u1[1], u1[0], 0x07060302u);
      A1.q.y = __builtin_amdgcn_perm(u1[3], u1[2], 0x07060302u);
      A1.q.z = __builtin_amdgcn_perm(u1[5], u1[4], 0x07060302u);
      A1.q.w = __builtin_amdgcn_perm(u1[7], u1[6], 0x07060302u);
      A2.q.x = __builtin_amdgcn_perm(u2[1], u2[0], 0x07060302u);
      A2.q.y = __builtin_amdgcn_perm(u2[3], u2[2], 0x07060302u);
      A2.q.z = __builtin_amdgcn_perm(u2[5], u2[4], 0x07060302u);
      A2.q.w = __builtin_amdgcn_perm(u2[7], u2[6], 0x07060302u);

      // 6 limb-products per expert-tile, all into the same fp32 accumulator
      acc0 = __builtin_amdgcn_mfma_f32_16x16x32_bf16(A0.v, W00.v, acc0, 0, 0, 0);
      acc0 = __builtin_amdgcn_mfma_f32_16x16x32_bf16(A0.v, W10.v, acc0, 0, 0, 0);
      acc0 = __builtin_amdgcn_mfma_f32_16x16x32_bf16(A1.v, W00.v, acc0, 0, 0, 0);
      acc0 = __builtin_amdgcn_mfma_f32_16x16x32_bf16(A1.v, W10.v, acc0, 0, 0, 0);
      acc0 = __builtin_amdgcn_mfma_f32_16x16x32_bf16(A0.v, W20.v, acc0, 0, 0, 0);
      acc0 = __builtin_amdgcn_mfma_f32_16x16x32_bf16(A2.v, W00.v, acc0, 0, 0, 0);
      acc1 = __builtin_amdgcn_mfma_f32_16x16x32_bf16(A0.v, W01.v, acc1, 0, 0, 0);
      acc1 = __builtin_amdgcn_mfma_f32_16x16x32_bf16(A0.v, W11.v, acc1, 0, 0, 0);
      acc1 = __builtin_amdgcn_mfma_f32_16x16x32_bf16(A1.v, W01.v, acc1, 0, 0, 0);
      acc1 = __builtin_amdgcn_mfma_f32_16x16x32_bf16(A1.v, W11.v, acc1, 0, 0, 0);
      acc1 = __builtin_amdgcn_mfma_f32_16x16x32_bf16(A0.v, W21.v, acc1, 0, 0, 0);
      acc1 = __builtin_amdgcn_mfma_f32_16x16x32_bf16(A2.v, W01.v, acc1, 0, 0, 0);
    }
    __syncthreads();   // drains vmcnt: chunk c+1 staged; flip buffers
  }

  // D layout (m89, verified): lane l reg r holds D[(l>>4)*4 + r][l&15]
  float* dst = wsp + ((size_t)kq * T + t0 + wv * 16) * NE;
#pragma unroll
  for (int r = 0; r < 4; ++r) {
    dst[(q * 4 + r) * NE + r15]      = acc0[r];
    dst[(q * 4 + r) * NE + 16 + r15] = acc1[r];
  }
}

// ---------- kernel 2: reduce partials + bias, top-4, softmax, scatter ------
__global__ void __launch_bounds__(256) router_topk(
    const float* __restrict__ wsp, const float* __restrict__ bias,
    float* __restrict__ out, int T, int KQ)
{
  const int tok = blockIdx.x * 256 + threadIdx.x;

  float lg[NE];
#pragma unroll
  for (int e = 0; e < NE; e += 4) {
    float4 bb = *(const float4*)(bias + e);
    lg[e] = bb.x; lg[e+1] = bb.y; lg[e+2] = bb.z; lg[e+3] = bb.w;
  }
  for (int qq = 0; qq < KQ; ++qq) {
    const float* p = wsp + ((size_t)qq * T + tok) * NE;
#pragma unroll
    for (int e = 0; e < NE; e += 4) {
      float4 v = *(const float4*)(p + e);
      lg[e] += v.x; lg[e+1] += v.y; lg[e+2] += v.z; lg[e+3] += v.w;
    }
  }

  float tv[4]; int ti[4];
#pragma unroll
  for (int kk = 0; kk < 4; ++kk) {
    float m = -INFINITY; int mi = 0;
#pragma unroll
    for (int e = 0; e < NE; ++e) {
      bool gt = lg[e] > m;          // strict >: lowest index wins ties (jax)
      m  = gt ? lg[e] : m;
      mi = gt ? e : mi;
    }
    tv[kk] = m; ti[kk] = mi;
#pragma unroll
    for (int e = 0; e < NE; ++e)
      lg[e] = (e == mi) ? -INFINITY : lg[e];
  }

  float e1 = __expf(tv[1] - tv[0]);
  float e2 = __expf(tv[2] - tv[0]);
  float e3 = __expf(tv[3] - tv[0]);
  float inv = 1.0f / (1.0f + e1 + e2 + e3);
  float pr[4] = {inv, e1 * inv, e2 * inv, e3 * inv};

  float* orow = out + (size_t)tok * NE;
#pragma unroll
  for (int g = 0; g < 8; ++g) {
    float4 v;
    float* vp = (float*)&v;
#pragma unroll
    for (int cb = 0; cb < 4; ++cb) {
      int e = g * 4 + cb;
      float xx = 0.f;
      xx = (e == ti[0]) ? pr[0] : xx;
      xx = (e == ti[1]) ? pr[1] : xx;
      xx = (e == ti[2]) ? pr[2] : xx;
      xx = (e == ti[3]) ? pr[3] : xx;
      vp[cb] = xx;
    }
    *(float4*)(orow + g * 4) = v;
  }
  float* oidx = out + (size_t)T * NE + (size_t)tok * 4;
  float4 iv;
  iv.x = (float)ti[0]; iv.y = (float)ti[1]; iv.z = (float)ti[2]; iv.w = (float)ti[3];
  *(float4*)oidx = iv;
}

extern "C" void kernel_launch(void* const* d_in, const int* in_sizes, int n_in,
                              void* d_out, int out_size, void* d_ws, size_t ws_size,
                              hipStream_t stream) {
  const float* hs   = (const float*)d_in[0];
  const float* w    = (const float*)d_in[1];
  const float* bias = (const float*)d_in[2];
  float* out        = (float*)d_out;

  unsigned int* wsB = (unsigned int*)d_ws;
  float* wsp        = (float*)((char*)d_ws + WSB_BYTES);

  const int T   = in_sizes[0] / HID;    // 16384
  const int ntg = T / TT;               // 256

  const size_t per_kq = (size_t)T * NE * 4;
  const int KQ = (ws_size >= WSB_BYTES + 4 * per_kq) ? 4 : 2;

  hipLaunchKernelGGL(wsplit_kernel, dim3(45), dim3(256), 0, stream, w, wsB);
  hipLaunchKernelGGL(router_mfma, dim3(ntg * KQ), dim3(THREADS), 0, stream,
                     hs, wsB, wsp, T, KQ, ntg);
  hipLaunchKernelGGL(router_topk, dim3(T / 256), dim3(256), 0, stream,
                     wsp, bias, out, T, KQ);
}